// Round 10
// baseline (105.839 us; speedup 1.0000x reference)
//
#include <hip/hip_runtime.h>

// ---------------------------------------------------------------------------
// Fused 5-layer GRU (SEQ=1, h0=0) + FC for MI355X (gfx950).  Round 11.
//
// R11: LDS diet -> 4 blocks/CU.  R10 left wall = 77us VALU busy + ~46us
// stall; residency was LDS-capped at 3 blocks/CU (43648 -> 44032 B alloc).
// Move the FC weights (2 f16x8 frags) + fc_b acc-inits (2 f32x4) from LDS
// into per-wave registers (16 VGPR, loaded once from global, loop-invariant
// -- unlike R3's failed 152-VGPR hoist this is tiny).  New LDS = 40960 B
// EXACTLY = 160KB/4 -> 4 blocks/CU (32 waves), grid 1024.  Worst case the
// 4th block is denied -> neutral at 3 blocks.
//
// Kept from R10: single-plane fp16 MFMA operands (v_mfma_f32_16x16x32_f16),
// cvt_pkrtz pack, halved permlane transform.
// Kept from R9: hardware v_rcp, exp2 scales folded into staged weights,
// launch_bounds(512,4) no-spill regime.
// Kept from R7: 2-tile interleave, shared A-frag/bias LDS reads with MFMA
// D!=C bias init, W_ST=40 padded LDS weights (conflict-free).
//
// Orientation: C^T = W @ h^T  (A = weight tile [gate][k], B = h^T [k][batch]).
// MFMA C/D layout (16x16x32): col = lane&15 = BATCH, row = q*4+i = gate row.
// ---------------------------------------------------------------------------

typedef __attribute__((ext_vector_type(8))) _Float16 f16x8;
typedef __attribute__((ext_vector_type(4))) float f32x4;
typedef __attribute__((ext_vector_type(2))) float f32x2;
typedef __attribute__((ext_vector_type(4))) unsigned int u32x4;

#define NLAYER 5
#define W_ST   40  // weight row stride in fp16 (80 B = 5 bank-quads: conflict-free)
#define NT     512 // block threads (8 waves)

__device__ __forceinline__ float fexp2(float x) {
#if __has_builtin(__builtin_amdgcn_exp2f)
    return __builtin_amdgcn_exp2f(x);
#else
    return exp2f(x);
#endif
}
__device__ __forceinline__ float frcp(float x) {
#if __has_builtin(__builtin_amdgcn_rcpf)
    return __builtin_amdgcn_rcpf(x);
#else
    return 1.0f / x;
#endif
}

// pack two f32 -> two fp16 (RTZ) in one word; rel err <= 2^-10, far below
// the fp16 weight quant (2^-11 RNE) + ref tolerance.
__device__ __forceinline__ unsigned cvt2(float f0, float f1) {
    unsigned r;
    asm("v_cvt_pkrtz_f16_f32 %0, %1, %2" : "=v"(r) : "v"(f0), "v"(f1));
    return r;
}

__device__ __forceinline__ f32x4 mfma16h(f16x8 a, f16x8 b, f32x4 c) {
    return __builtin_amdgcn_mfma_f32_16x16x32_f16(a, b, c, 0, 0, 0);
}

// In-register 16-lane-group exchange (gfx950):
//   in : x = [X0,X1,X2,X3], y = [Y0,Y1,Y2,Y3]   (16-lane groups)
//   out: x = [X0,X2,Y0,Y2], y = [X1,X3,Y1,Y3]
__device__ __forceinline__ void xpose_pair(unsigned &x, unsigned &y) {
    asm("v_permlane32_swap_b32 %0, %1" : "+v"(x), "+v"(y));
    asm("v_permlane16_swap_b32 %0, %1" : "+v"(x), "+v"(y));
}

__device__ __forceinline__ f32x2 mk2(float a, float b) { f32x2 v; v.x = a; v.y = b; return v; }
__device__ __forceinline__ f32x2 exp2v(f32x2 v) { f32x2 r; r.x = fexp2(v.x); r.y = fexp2(v.y); return r; }
__device__ __forceinline__ f32x2 rcpv(f32x2 v)  { f32x2 r; r.x = frcp(v.x);  r.y = frcp(v.y);  return r; }

// h = (1-z)*n = sigmoid(-az)*tanh(an + sigmoid(ar)*cn)
//   = [ez*(1-en)] / [(1+ez)*(1+en)]
// Args are PRE-SCALED at staging: ar,az by -log2e; an,cn by -2log2e, so
// er = exp2(ar'), ez = exp2(az'), en = exp2(an' + r*cn') directly.
__device__ __forceinline__ f32x2 gru_act2(f32x2 ar, f32x2 az, f32x2 an, f32x2 cn) {
    f32x2 er  = exp2v(ar);
    f32x2 ez  = exp2v(az);
    f32x2 r   = rcpv(er + 1.0f);
    f32x2 a2  = an + r * cn;
    f32x2 en  = exp2v(a2);
    f32x2 num = ez - ez * en;
    f32x2 den = (ez + 1.0f) * (en + 1.0f);
    return num * rcpv(den);
}

struct __align__(16) Lds {
    _Float16 wA[NLAYER * 96 * W_ST];              // 38400 B  [l][gate-row][k], row stride 40
    float bsum[NLAYER * 96];                      //  1920 B  scaled biases
    float cn_[NLAYER * 32];                       //   640 B  scaled b_hh n-gate
};                                                // total 40960 B == 160KB/4 -> 4 blocks/CU

union BU { u32x4 w; f16x8 v; };

__global__ __launch_bounds__(NT, 4) void gru_fused(
    const float* __restrict__ x, const float* __restrict__ w_ih,
    const float* __restrict__ b_ih, const float* __restrict__ b_hh,
    const float* __restrict__ fc_w, const float* __restrict__ fc_b,
    float* __restrict__ out, int nPairs)
{
    __shared__ Lds s;
    const int tid = threadIdx.x;
    const float NL2E = -1.4426950408889634f;  // -log2(e)

    // ---- stage GRU weights / biases into LDS (once per block), pre-scaled ----
    for (int i = tid; i < NLAYER * 96 * 32; i += NT) {
        int r = i >> 5, c = i & 31;
        int g = r % 96;                         // gate row within layer
        float sc = (g < 64) ? NL2E : 2.0f * NL2E;
        s.wA[r * W_ST + c] = (_Float16)(w_ih[i] * sc);   // RNE, rel 2^-11
    }
    for (int i = tid; i < NLAYER * 96; i += NT) {
        int c = i % 96;
        float v = b_ih[i] + (c < 64 ? b_hh[i] : 0.0f);
        s.bsum[i] = v * ((c < 64) ? NL2E : 2.0f * NL2E);
    }
    for (int i = tid; i < NLAYER * 32; i += NT) {
        int l = i >> 5, c = i & 31;
        s.cn_[i] = b_hh[l * 96 + 64 + c] * (2.0f * NL2E);
    }
    __syncthreads();

    const int lane = tid & 63;
    const int n0 = lane & 15;     // batch-col (B n-index / C col); A row m
    const int q  = lane >> 4;     // k-group (A/B), row-group (C/D)

    // ---- FC weights + bias in registers (loop-invariant, 16 VGPR) ----
    f16x8 F0, F1;
    {
        const float* p0 = fc_w + (size_t)(n0 * 32 + q * 8);
        const float* p1 = fc_w + (size_t)((16 + n0) * 32 + q * 8);
        f32x4 a0 = *(const f32x4*)p0, a1 = *(const f32x4*)(p0 + 4);
        f32x4 b0 = *(const f32x4*)p1, b1 = *(const f32x4*)(p1 + 4);
        BU U0, U1;
        U0.w[0] = cvt2(a0[0], a0[1]); U0.w[1] = cvt2(a0[2], a0[3]);
        U0.w[2] = cvt2(a1[0], a1[1]); U0.w[3] = cvt2(a1[2], a1[3]);
        U1.w[0] = cvt2(b0[0], b0[1]); U1.w[1] = cvt2(b0[2], b0[3]);
        U1.w[2] = cvt2(b1[0], b1[1]); U1.w[3] = cvt2(b1[2], b1[3]);
        F0 = U0.v; F1 = U1.v;
    }
    f32x4 OB0 = *(const f32x4*)(fc_b + q * 4);
    f32x4 OB1 = *(const f32x4*)(fc_b + 16 + q * 4);

    const int waveId  = (int)((blockIdx.x * (unsigned)NT + tid) >> 6);
    const int nWavesG = (int)((gridDim.x * (unsigned)NT) >> 6);

    for (int t = waveId; t < nPairs; t += nWavesG) {
        const int rowBase = t * 32;  // tile A rows +0..15, tile B rows +16..31

        // ---- load x as fp16 B-frags for both tiles ----
        const float* xpA = x + (size_t)(rowBase + n0) * 32 + q * 8;
        const float* xpB = x + (size_t)(rowBase + 16 + n0) * 32 + q * 8;
        f32x4 xaA = *(const f32x4*)xpA, xbA = *(const f32x4*)(xpA + 4);
        f32x4 xaB = *(const f32x4*)xpB, xbB = *(const f32x4*)(xpB + 4);
        BU BA, BB;
        BA.w[0] = cvt2(xaA[0], xaA[1]); BA.w[1] = cvt2(xaA[2], xaA[3]);
        BA.w[2] = cvt2(xbA[0], xbA[1]); BA.w[3] = cvt2(xbA[2], xbA[3]);
        BB.w[0] = cvt2(xaB[0], xaB[1]); BB.w[1] = cvt2(xaB[2], xaB[3]);
        BB.w[2] = cvt2(xbB[0], xbB[1]); BB.w[3] = cvt2(xbB[2], xbB[3]);
        f16x8 bA = BA.v, bB = BB.v;

        #pragma unroll
        for (int l = 0; l < NLAYER; ++l) {
            const _Float16* wb = s.wA + l * 96 * W_ST;
            const float* bs = s.bsum + l * 96;

            f32x4 cR0A, cR1A, cZ0A, cZ1A, cN0A, cN1A;
            f32x4 cR0B, cR1B, cZ0B, cZ1B, cN0B, cN1B;

            // per gate-tile: 1 A-frag LDS read + 1 bias LDS read -> 2 MFMAs
            // (one per batch-tile), each initing from bias via D != C.
            {
                f16x8 a = *(const f16x8*)(wb + (0 * 16 + n0) * W_ST + q * 8);
                f32x4 cb = *(const f32x4*)(bs + 0 + q * 4);
                cR0A = mfma16h(a, bA, cb);
                cR0B = mfma16h(a, bB, cb);
            }
            {
                f16x8 a = *(const f16x8*)(wb + (1 * 16 + n0) * W_ST + q * 8);
                f32x4 cb = *(const f32x4*)(bs + 16 + q * 4);
                cR1A = mfma16h(a, bA, cb);
                cR1B = mfma16h(a, bB, cb);
            }
            {
                f16x8 a = *(const f16x8*)(wb + (2 * 16 + n0) * W_ST + q * 8);
                f32x4 cb = *(const f32x4*)(bs + 32 + q * 4);
                cZ0A = mfma16h(a, bA, cb);
                cZ0B = mfma16h(a, bB, cb);
            }
            {
                f16x8 a = *(const f16x8*)(wb + (3 * 16 + n0) * W_ST + q * 8);
                f32x4 cb = *(const f32x4*)(bs + 48 + q * 4);
                cZ1A = mfma16h(a, bA, cb);
                cZ1B = mfma16h(a, bB, cb);
            }
            {
                f16x8 a = *(const f16x8*)(wb + (4 * 16 + n0) * W_ST + q * 8);
                f32x4 cb = *(const f32x4*)(bs + 64 + q * 4);
                cN0A = mfma16h(a, bA, cb);
                cN0B = mfma16h(a, bB, cb);
            }
            {
                f16x8 a = *(const f16x8*)(wb + (5 * 16 + n0) * W_ST + q * 8);
                f32x4 cb = *(const f32x4*)(bs + 80 + q * 4);
                cN1A = mfma16h(a, bA, cb);
                cN1B = mfma16h(a, bB, cb);
            }

            f32x4 vc0 = *(const f32x4*)(s.cn_ + l * 32 + 0  + q * 4);
            f32x4 vc1 = *(const f32x4*)(s.cn_ + l * 32 + 16 + q * 4);

            // ---- activations + pack + permlane transform, tile A ----
            {
                f32x2 hA = gru_act2(mk2(cR0A[0], cR0A[1]), mk2(cZ0A[0], cZ0A[1]),
                                    mk2(cN0A[0], cN0A[1]), mk2(vc0[0], vc0[1]));
                f32x2 hB = gru_act2(mk2(cR0A[2], cR0A[3]), mk2(cZ0A[2], cZ0A[3]),
                                    mk2(cN0A[2], cN0A[3]), mk2(vc0[2], vc0[3]));
                f32x2 hC = gru_act2(mk2(cR1A[0], cR1A[1]), mk2(cZ1A[0], cZ1A[1]),
                                    mk2(cN1A[0], cN1A[1]), mk2(vc1[0], vc1[1]));
                f32x2 hD = gru_act2(mk2(cR1A[2], cR1A[3]), mk2(cZ1A[2], cZ1A[3]),
                                    mk2(cN1A[2], cN1A[3]), mk2(vc1[2], vc1[3]));
                unsigned hw0 = cvt2(hA.x, hA.y);   // hids 4q+{0,1}
                unsigned hw1 = cvt2(hB.x, hB.y);   // hids 4q+{2,3}
                unsigned hw2 = cvt2(hC.x, hC.y);   // hids 16+4q+{0,1}
                unsigned hw3 = cvt2(hD.x, hD.y);   // hids 16+4q+{2,3}
                xpose_pair(hw0, hw2);   // hw0 -> B elems {0,1}, hw2 -> {4,5}
                xpose_pair(hw1, hw3);   // hw1 -> B elems {2,3}, hw3 -> {6,7}
                BA.w[0] = hw0; BA.w[1] = hw1; BA.w[2] = hw2; BA.w[3] = hw3;
                bA = BA.v;
            }
            // ---- activations + pack + permlane transform, tile B ----
            {
                f32x2 hA = gru_act2(mk2(cR0B[0], cR0B[1]), mk2(cZ0B[0], cZ0B[1]),
                                    mk2(cN0B[0], cN0B[1]), mk2(vc0[0], vc0[1]));
                f32x2 hB = gru_act2(mk2(cR0B[2], cR0B[3]), mk2(cZ0B[2], cZ0B[3]),
                                    mk2(cN0B[2], cN0B[3]), mk2(vc0[2], vc0[3]));
                f32x2 hC = gru_act2(mk2(cR1B[0], cR1B[1]), mk2(cZ1B[0], cZ1B[1]),
                                    mk2(cN1B[0], cN1B[1]), mk2(vc1[0], vc1[1]));
                f32x2 hD = gru_act2(mk2(cR1B[2], cR1B[3]), mk2(cZ1B[2], cZ1B[3]),
                                    mk2(cN1B[2], cN1B[3]), mk2(vc1[2], vc1[3]));
                unsigned hw0 = cvt2(hA.x, hA.y);
                unsigned hw1 = cvt2(hB.x, hB.y);
                unsigned hw2 = cvt2(hC.x, hC.y);
                unsigned hw3 = cvt2(hD.x, hD.y);
                xpose_pair(hw0, hw2);
                xpose_pair(hw1, hw3);
                BB.w[0] = hw0; BB.w[1] = hw1; BB.w[2] = hw2; BB.w[3] = hw3;
                bB = BB.v;
            }
        }

        // ---- FC: out^T = fc_w @ h5^T + fc_b, both tiles (regs only) ----
        f32x4 o0A = mfma16h(F0, bA, OB0);
        f32x4 o1A = mfma16h(F1, bA, OB1);
        f32x4 o0B = mfma16h(F0, bB, OB0);
        f32x4 o1B = mfma16h(F1, bB, OB1);

        // lane holds out[batch][emb = t*16 + q*4 + i]
        float* opA = out + (size_t)(rowBase + n0) * 32;
        float* opB = out + (size_t)(rowBase + 16 + n0) * 32;
        *(f32x4*)(opA + 0  + q * 4) = o0A;
        *(f32x4*)(opA + 16 + q * 4) = o1A;
        *(f32x4*)(opB + 0  + q * 4) = o0B;
        *(f32x4*)(opB + 16 + q * 4) = o1B;
    }
}

extern "C" void kernel_launch(void* const* d_in, const int* in_sizes, int n_in,
                              void* d_out, int out_size, void* d_ws, size_t ws_size,
                              hipStream_t stream) {
    (void)n_in; (void)d_ws; (void)ws_size; (void)out_size;
    const float* x    = (const float*)d_in[0];
    const float* w_ih = (const float*)d_in[1];
    // d_in[2] = w_hh: unused (h0 == 0, T == 1)
    const float* b_ih = (const float*)d_in[3];
    const float* b_hh = (const float*)d_in[4];
    const float* fc_w = (const float*)d_in[5];
    const float* fc_b = (const float*)d_in[6];
    float* out = (float*)d_out;

    const int batch  = in_sizes[0] / 32;   // 1048576
    const int nPairs = batch / 32;         // 32768 tile-pairs (2 x 16 rows)

    // 1024 blocks x 512 thr: LDS 40960 B = 160KB/4 -> 4 blocks/CU (32 waves),
    // launch_bounds(512,4) keeps the allocator at the no-spill cap.
    // 8192 waves, 4 pairs/wave.
    gru_fused<<<1024, NT, 0, stream>>>(x, w_ih, b_ih, b_hh, fc_w, fc_b, out, nPairs);
}

// Round 11
// 103.987 us; speedup vs baseline: 1.0178x; 1.0178x over previous
//
#include <hip/hip_runtime.h>

// ---------------------------------------------------------------------------
// Fused 5-layer GRU (SEQ=1, h0=0) + FC for MI355X (gfx950).  Round 12.
//
// R12: R11's LDS=40960 was EXACTLY 160KB/4 -> runtime reserve denied the 4th
// block (occupancy stuck at 38%).  Replace the W_ST=40 padding with an XOR
// swizzle at stride 32: element i stored at i ^ ((row&7)<<3) (bijective;
// read quad index ((4r+q)%8)^(r&7) covers all 8 bank-quads exactly twice
// per half-wave = minimal 2-way, same as the padded layout).  wA shrinks
// 38400 -> 30720 B; total LDS = 33280 B -> 4 blocks/CU (133KB) with margin.
// Single-lever change: everything else identical to R11 for a clean
// occupancy A/B.  (If occupancy still doesn't rise, residency wasn't
// LDS-capped and the next lever is LDS-read-count reduction.)
//
// Kept from R11: FC weights + fc_b in registers; grid 1024.
// Kept from R10: single-plane fp16 MFMA (v_mfma_f32_16x16x32_f16),
// cvt_pkrtz pack, halved permlane transform.
// Kept from R9: hardware v_rcp, exp2 scales folded into staged weights,
// launch_bounds(512,4) no-spill regime.
// Kept from R7: 2-tile interleave, shared A-frag/bias reads, MFMA D!=C
// bias init.
//
// Orientation: C^T = W @ h^T  (A = weight tile [gate][k], B = h^T [k][batch]).
// MFMA C/D layout (16x16x32): col = lane&15 = BATCH, row = q*4+i = gate row.
// ---------------------------------------------------------------------------

typedef __attribute__((ext_vector_type(8))) _Float16 f16x8;
typedef __attribute__((ext_vector_type(4))) float f32x4;
typedef __attribute__((ext_vector_type(2))) float f32x2;
typedef __attribute__((ext_vector_type(4))) unsigned int u32x4;

#define NLAYER 5
#define NT     512 // block threads (8 waves)

__device__ __forceinline__ float fexp2(float x) {
#if __has_builtin(__builtin_amdgcn_exp2f)
    return __builtin_amdgcn_exp2f(x);
#else
    return exp2f(x);
#endif
}
__device__ __forceinline__ float frcp(float x) {
#if __has_builtin(__builtin_amdgcn_rcpf)
    return __builtin_amdgcn_rcpf(x);
#else
    return 1.0f / x;
#endif
}

// pack two f32 -> two fp16 (RTZ) in one word; rel err <= 2^-10, far below
// the fp16 weight quant (2^-11 RNE) + ref tolerance.
__device__ __forceinline__ unsigned cvt2(float f0, float f1) {
    unsigned r;
    asm("v_cvt_pkrtz_f16_f32 %0, %1, %2" : "=v"(r) : "v"(f0), "v"(f1));
    return r;
}

__device__ __forceinline__ f32x4 mfma16h(f16x8 a, f16x8 b, f32x4 c) {
    return __builtin_amdgcn_mfma_f32_16x16x32_f16(a, b, c, 0, 0, 0);
}

// In-register 16-lane-group exchange (gfx950):
//   in : x = [X0,X1,X2,X3], y = [Y0,Y1,Y2,Y3]   (16-lane groups)
//   out: x = [X0,X2,Y0,Y2], y = [X1,X3,Y1,Y3]
__device__ __forceinline__ void xpose_pair(unsigned &x, unsigned &y) {
    asm("v_permlane32_swap_b32 %0, %1" : "+v"(x), "+v"(y));
    asm("v_permlane16_swap_b32 %0, %1" : "+v"(x), "+v"(y));
}

__device__ __forceinline__ f32x2 mk2(float a, float b) { f32x2 v; v.x = a; v.y = b; return v; }
__device__ __forceinline__ f32x2 exp2v(f32x2 v) { f32x2 r; r.x = fexp2(v.x); r.y = fexp2(v.y); return r; }
__device__ __forceinline__ f32x2 rcpv(f32x2 v)  { f32x2 r; r.x = frcp(v.x);  r.y = frcp(v.y);  return r; }

// h = (1-z)*n = sigmoid(-az)*tanh(an + sigmoid(ar)*cn)
//   = [ez*(1-en)] / [(1+ez)*(1+en)]
// Args are PRE-SCALED at staging: ar,az by -log2e; an,cn by -2log2e, so
// er = exp2(ar'), ez = exp2(az'), en = exp2(an' + r*cn') directly.
__device__ __forceinline__ f32x2 gru_act2(f32x2 ar, f32x2 az, f32x2 an, f32x2 cn) {
    f32x2 er  = exp2v(ar);
    f32x2 ez  = exp2v(az);
    f32x2 r   = rcpv(er + 1.0f);
    f32x2 a2  = an + r * cn;
    f32x2 en  = exp2v(a2);
    f32x2 num = ez - ez * en;
    f32x2 den = (ez + 1.0f) * (en + 1.0f);
    return num * rcpv(den);
}

struct __align__(16) Lds {
    _Float16 wA[NLAYER * 96 * 32];                // 30720 B  [l][gate-row][k], XOR-swizzled
    float bsum[NLAYER * 96];                      //  1920 B  scaled biases
    float cn_[NLAYER * 32];                       //   640 B  scaled b_hh n-gate
};                                                // total 33280 B -> 4 blocks/CU (133KB)

union BU { u32x4 w; f16x8 v; };

__global__ __launch_bounds__(NT, 4) void gru_fused(
    const float* __restrict__ x, const float* __restrict__ w_ih,
    const float* __restrict__ b_ih, const float* __restrict__ b_hh,
    const float* __restrict__ fc_w, const float* __restrict__ fc_b,
    float* __restrict__ out, int nPairs)
{
    __shared__ Lds s;
    const int tid = threadIdx.x;
    const float NL2E = -1.4426950408889634f;  // -log2(e)

    // ---- stage GRU weights / biases into LDS (once per block), pre-scaled.
    // Swizzle: element i stored at i ^ ((row&7)<<3)  (bijective; flips elem
    // bits 3-5 keyed on row bits 0-2; 16B groups stay contiguous). ----
    for (int i = tid; i < NLAYER * 96 * 32; i += NT) {
        int r = i >> 5;
        int g = r % 96;                         // gate row within layer
        float sc = (g < 64) ? NL2E : 2.0f * NL2E;
        s.wA[i ^ ((r & 7) << 3)] = (_Float16)(w_ih[i] * sc);   // RNE, rel 2^-11
    }
    for (int i = tid; i < NLAYER * 96; i += NT) {
        int c = i % 96;
        float v = b_ih[i] + (c < 64 ? b_hh[i] : 0.0f);
        s.bsum[i] = v * ((c < 64) ? NL2E : 2.0f * NL2E);
    }
    for (int i = tid; i < NLAYER * 32; i += NT) {
        int l = i >> 5, c = i & 31;
        s.cn_[i] = b_hh[l * 96 + 64 + c] * (2.0f * NL2E);
    }
    __syncthreads();

    const int lane = tid & 63;
    const int n0 = lane & 15;     // batch-col (B n-index / C col); A row m
    const int q  = lane >> 4;     // k-group (A/B), row-group (C/D)
    const int swz = (n0 & 7) << 3;  // A-frag read swizzle key (row = g*16+n0)

    // ---- FC weights + bias in registers (loop-invariant, 16 VGPR) ----
    f16x8 F0, F1;
    {
        const float* p0 = fc_w + (size_t)(n0 * 32 + q * 8);
        const float* p1 = fc_w + (size_t)((16 + n0) * 32 + q * 8);
        f32x4 a0 = *(const f32x4*)p0, a1 = *(const f32x4*)(p0 + 4);
        f32x4 b0 = *(const f32x4*)p1, b1 = *(const f32x4*)(p1 + 4);
        BU U0, U1;
        U0.w[0] = cvt2(a0[0], a0[1]); U0.w[1] = cvt2(a0[2], a0[3]);
        U0.w[2] = cvt2(a1[0], a1[1]); U0.w[3] = cvt2(a1[2], a1[3]);
        U1.w[0] = cvt2(b0[0], b0[1]); U1.w[1] = cvt2(b0[2], b0[3]);
        U1.w[2] = cvt2(b1[0], b1[1]); U1.w[3] = cvt2(b1[2], b1[3]);
        F0 = U0.v; F1 = U1.v;
    }
    f32x4 OB0 = *(const f32x4*)(fc_b + q * 4);
    f32x4 OB1 = *(const f32x4*)(fc_b + 16 + q * 4);

    const int waveId  = (int)((blockIdx.x * (unsigned)NT + tid) >> 6);
    const int nWavesG = (int)((gridDim.x * (unsigned)NT) >> 6);

    for (int t = waveId; t < nPairs; t += nWavesG) {
        const int rowBase = t * 32;  // tile A rows +0..15, tile B rows +16..31

        // ---- load x as fp16 B-frags for both tiles ----
        const float* xpA = x + (size_t)(rowBase + n0) * 32 + q * 8;
        const float* xpB = x + (size_t)(rowBase + 16 + n0) * 32 + q * 8;
        f32x4 xaA = *(const f32x4*)xpA, xbA = *(const f32x4*)(xpA + 4);
        f32x4 xaB = *(const f32x4*)xpB, xbB = *(const f32x4*)(xpB + 4);
        BU BA, BB;
        BA.w[0] = cvt2(xaA[0], xaA[1]); BA.w[1] = cvt2(xaA[2], xaA[3]);
        BA.w[2] = cvt2(xbA[0], xbA[1]); BA.w[3] = cvt2(xbA[2], xbA[3]);
        BB.w[0] = cvt2(xaB[0], xaB[1]); BB.w[1] = cvt2(xaB[2], xaB[3]);
        BB.w[2] = cvt2(xbB[0], xbB[1]); BB.w[3] = cvt2(xbB[2], xbB[3]);
        f16x8 bA = BA.v, bB = BB.v;

        #pragma unroll
        for (int l = 0; l < NLAYER; ++l) {
            const _Float16* wb = s.wA + l * 96 * 32;
            const float* bs = s.bsum + l * 96;
            const int a0i = ((n0 * 32) + q * 8) ^ swz;   // gate-0 frag index

            f32x4 cR0A, cR1A, cZ0A, cZ1A, cN0A, cN1A;
            f32x4 cR0B, cR1B, cZ0B, cZ1B, cN0B, cN1B;

            // per gate-tile: 1 swizzled A-frag LDS read + 1 bias read -> 2
            // MFMAs (one per batch-tile), each initing from bias via D != C.
            // gate g offset = g*512 elements (multiple of 64 -> swizzle-safe).
            {
                f16x8 a = *(const f16x8*)(wb + a0i + 0 * 512);
                f32x4 cb = *(const f32x4*)(bs + 0 + q * 4);
                cR0A = mfma16h(a, bA, cb);
                cR0B = mfma16h(a, bB, cb);
            }
            {
                f16x8 a = *(const f16x8*)(wb + a0i + 1 * 512);
                f32x4 cb = *(const f32x4*)(bs + 16 + q * 4);
                cR1A = mfma16h(a, bA, cb);
                cR1B = mfma16h(a, bB, cb);
            }
            {
                f16x8 a = *(const f16x8*)(wb + a0i + 2 * 512);
                f32x4 cb = *(const f32x4*)(bs + 32 + q * 4);
                cZ0A = mfma16h(a, bA, cb);
                cZ0B = mfma16h(a, bB, cb);
            }
            {
                f16x8 a = *(const f16x8*)(wb + a0i + 3 * 512);
                f32x4 cb = *(const f32x4*)(bs + 48 + q * 4);
                cZ1A = mfma16h(a, bA, cb);
                cZ1B = mfma16h(a, bB, cb);
            }
            {
                f16x8 a = *(const f16x8*)(wb + a0i + 4 * 512);
                f32x4 cb = *(const f32x4*)(bs + 64 + q * 4);
                cN0A = mfma16h(a, bA, cb);
                cN0B = mfma16h(a, bB, cb);
            }
            {
                f16x8 a = *(const f16x8*)(wb + a0i + 5 * 512);
                f32x4 cb = *(const f32x4*)(bs + 80 + q * 4);
                cN1A = mfma16h(a, bA, cb);
                cN1B = mfma16h(a, bB, cb);
            }

            f32x4 vc0 = *(const f32x4*)(s.cn_ + l * 32 + 0  + q * 4);
            f32x4 vc1 = *(const f32x4*)(s.cn_ + l * 32 + 16 + q * 4);

            // ---- activations + pack + permlane transform, tile A ----
            {
                f32x2 hA = gru_act2(mk2(cR0A[0], cR0A[1]), mk2(cZ0A[0], cZ0A[1]),
                                    mk2(cN0A[0], cN0A[1]), mk2(vc0[0], vc0[1]));
                f32x2 hB = gru_act2(mk2(cR0A[2], cR0A[3]), mk2(cZ0A[2], cZ0A[3]),
                                    mk2(cN0A[2], cN0A[3]), mk2(vc0[2], vc0[3]));
                f32x2 hC = gru_act2(mk2(cR1A[0], cR1A[1]), mk2(cZ1A[0], cZ1A[1]),
                                    mk2(cN1A[0], cN1A[1]), mk2(vc1[0], vc1[1]));
                f32x2 hD = gru_act2(mk2(cR1A[2], cR1A[3]), mk2(cZ1A[2], cZ1A[3]),
                                    mk2(cN1A[2], cN1A[3]), mk2(vc1[2], vc1[3]));
                unsigned hw0 = cvt2(hA.x, hA.y);   // hids 4q+{0,1}
                unsigned hw1 = cvt2(hB.x, hB.y);   // hids 4q+{2,3}
                unsigned hw2 = cvt2(hC.x, hC.y);   // hids 16+4q+{0,1}
                unsigned hw3 = cvt2(hD.x, hD.y);   // hids 16+4q+{2,3}
                xpose_pair(hw0, hw2);   // hw0 -> B elems {0,1}, hw2 -> {4,5}
                xpose_pair(hw1, hw3);   // hw1 -> B elems {2,3}, hw3 -> {6,7}
                BA.w[0] = hw0; BA.w[1] = hw1; BA.w[2] = hw2; BA.w[3] = hw3;
                bA = BA.v;
            }
            // ---- activations + pack + permlane transform, tile B ----
            {
                f32x2 hA = gru_act2(mk2(cR0B[0], cR0B[1]), mk2(cZ0B[0], cZ0B[1]),
                                    mk2(cN0B[0], cN0B[1]), mk2(vc0[0], vc0[1]));
                f32x2 hB = gru_act2(mk2(cR0B[2], cR0B[3]), mk2(cZ0B[2], cZ0B[3]),
                                    mk2(cN0B[2], cN0B[3]), mk2(vc0[2], vc0[3]));
                f32x2 hC = gru_act2(mk2(cR1B[0], cR1B[1]), mk2(cZ1B[0], cZ1B[1]),
                                    mk2(cN1B[0], cN1B[1]), mk2(vc1[0], vc1[1]));
                f32x2 hD = gru_act2(mk2(cR1B[2], cR1B[3]), mk2(cZ1B[2], cZ1B[3]),
                                    mk2(cN1B[2], cN1B[3]), mk2(vc1[2], vc1[3]));
                unsigned hw0 = cvt2(hA.x, hA.y);
                unsigned hw1 = cvt2(hB.x, hB.y);
                unsigned hw2 = cvt2(hC.x, hC.y);
                unsigned hw3 = cvt2(hD.x, hD.y);
                xpose_pair(hw0, hw2);
                xpose_pair(hw1, hw3);
                BB.w[0] = hw0; BB.w[1] = hw1; BB.w[2] = hw2; BB.w[3] = hw3;
                bB = BB.v;
            }
        }

        // ---- FC: out^T = fc_w @ h5^T + fc_b, both tiles (regs only) ----
        f32x4 o0A = mfma16h(F0, bA, OB0);
        f32x4 o1A = mfma16h(F1, bA, OB1);
        f32x4 o0B = mfma16h(F0, bB, OB0);
        f32x4 o1B = mfma16h(F1, bB, OB1);

        // lane holds out[batch][emb = t*16 + q*4 + i]
        float* opA = out + (size_t)(rowBase + n0) * 32;
        float* opB = out + (size_t)(rowBase + 16 + n0) * 32;
        *(f32x4*)(opA + 0  + q * 4) = o0A;
        *(f32x4*)(opA + 16 + q * 4) = o1A;
        *(f32x4*)(opB + 0  + q * 4) = o0B;
        *(f32x4*)(opB + 16 + q * 4) = o1B;
    }
}

extern "C" void kernel_launch(void* const* d_in, const int* in_sizes, int n_in,
                              void* d_out, int out_size, void* d_ws, size_t ws_size,
                              hipStream_t stream) {
    (void)n_in; (void)d_ws; (void)ws_size; (void)out_size;
    const float* x    = (const float*)d_in[0];
    const float* w_ih = (const float*)d_in[1];
    // d_in[2] = w_hh: unused (h0 == 0, T == 1)
    const float* b_ih = (const float*)d_in[3];
    const float* b_hh = (const float*)d_in[4];
    const float* fc_w = (const float*)d_in[5];
    const float* fc_b = (const float*)d_in[6];
    float* out = (float*)d_out;

    const int batch  = in_sizes[0] / 32;   // 1048576
    const int nPairs = batch / 32;         // 32768 tile-pairs (2 x 16 rows)

    // 1024 blocks x 512 thr: LDS 33280 B -> 4 blocks/CU (133KB, reserve-safe),
    // launch_bounds(512,4) keeps the allocator at the no-spill cap.
    // 8192 waves, 4 pairs/wave.
    gru_fused<<<1024, NT, 0, stream>>>(x, w_ih, b_ih, b_hh, fc_w, fc_b, out, nPairs);
}